// Round 4
// baseline (163.027 us; speedup 1.0000x reference)
//
#include <hip/hip_runtime.h>
#include <math.h>

// Problem dims (fixed by reference)
#define BN  256   // batch
#define IN  512
#define HID 1024
#define OUT 512

#define KS1 16            // K-split layer 1: 512 -> 16 chunks of 32
#define C1  (IN / KS1)    // 32
#define G   8             // batch rows per thread in K1

typedef float f32x2 __attribute__((ext_vector_type(2)));

// hard-concrete deterministic gate: clip(sigmoid(q)*1.2 - 0.1, 0, 1)
__device__ __forceinline__ float gate(float q) {
    float s = 1.0f / (1.0f + expf(-q));
    return fminf(fmaxf(fmaf(s, 1.2f, -0.1f), 0.0f), 1.0f);
}

// K1 (unchanged from round 3, proven): layer-1 partial products.
// hp[ks][b][j] = prod_{i in chunk ks} (1 - (1 - x*z1)*W1)
// thread: 4 j (j0 = tid*4) x 8 b as 4 f32x2 pairs. grid (bt=32, ks=16).
__global__ __launch_bounds__(256) void k_layer1(
        const float* __restrict__ x, const float* __restrict__ qz1,
        const float* __restrict__ W1, float* __restrict__ hp) {
    __shared__ float sm[C1][G];    // negm[i][b] = x*z1 - 1  (= -(1-xin))
    const int tid = threadIdx.x;
    const int b0  = blockIdx.x * G;
    const int ks  = blockIdx.y;
    const int i0  = ks * C1;

    {   // stage: exactly one element per thread (C1*G == 256)
        int ii = tid >> 3, b = tid & 7;
        float z = gate(qz1[i0 + ii]);
        sm[ii][b] = fmaf(x[(size_t)(b0 + b) * IN + i0 + ii], z, -1.0f);
    }
    __syncthreads();

    const int j0 = tid * 4;
    const f32x2 one2 = {1.0f, 1.0f};
    f32x2 acc[4][4];
#pragma unroll
    for (int j = 0; j < 4; ++j)
#pragma unroll
        for (int p = 0; p < 4; ++p) acc[j][p] = one2;

    const float* wp = W1 + (size_t)i0 * HID + j0;
#pragma unroll 4
    for (int ii = 0; ii < C1; ++ii) {
        float4 w4  = *reinterpret_cast<const float4*>(wp + (size_t)ii * HID);
        float4 alo = *reinterpret_cast<const float4*>(&sm[ii][0]);
        float4 ahi = *reinterpret_cast<const float4*>(&sm[ii][4]);
        f32x2 ap[4];
        ap[0] = f32x2{alo.x, alo.y}; ap[1] = f32x2{alo.z, alo.w};
        ap[2] = f32x2{ahi.x, ahi.y}; ap[3] = f32x2{ahi.z, ahi.w};
        float wq[4] = {w4.x, w4.y, w4.z, w4.w};
#pragma unroll
        for (int j = 0; j < 4; ++j) {
            f32x2 wj = {wq[j], wq[j]};
#pragma unroll
            for (int p = 0; p < 4; ++p) {
                acc[j][p] *= ap[p] * wj + one2;   // v_pk_fma + v_pk_mul
            }
        }
    }

    float* op = hp + ((size_t)ks * BN + b0) * HID + j0;
#pragma unroll
    for (int b = 0; b < G; ++b) {
        const int p = b >> 1, h = b & 1;
        float4 v = {acc[0][p][h], acc[1][p][h], acc[2][p][h], acc[3][p][h]};
        *reinterpret_cast<float4*>(op + (size_t)b * HID) = v;
    }
}

// K2: layer-2 full-K fused with final combine (k_final eliminated).
// grid 256 blocks x 512 threads: jt = bx&7 (64 j), bt = bx>>3 (8 b).
// Each wave = 64 consecutive j, one b row -> W2 reads 256B coalesced,
// sm reads wave-uniform (broadcast, conflict-free).
// out[b][j] = 1 - prod_{i<1024} (1 - h[b][i]*z2[i]*W2[i][j])
__global__ __launch_bounds__(512) void k_layer2f(
        const float* __restrict__ hp, const float* __restrict__ qz2,
        const float* __restrict__ W2, float* __restrict__ out) {
    __shared__ float sm[G][HID];   // 32 KB: negx2[b][i] = -(h*z2)
    const int tid = threadIdx.x;
    const int jt  = blockIdx.x & 7;
    const int bt  = blockIdx.x >> 3;
    const int b0  = bt * G;
    const int j   = jt * 64 + (tid & 63);
    const int bb  = tid >> 6;      // wave-uniform batch row

    // stage: 8 x 1024 elems, 16 per thread, lanes -> consecutive i (coalesced)
#pragma unroll 4
    for (int p = 0; p < 16; ++p) {
        int e  = p * 512 + tid;
        int b  = e >> 10;
        int ii = e & 1023;
        size_t gi = (size_t)(b0 + b) * HID + ii;
        float h = hp[gi];
#pragma unroll
        for (int k = 1; k < KS1; ++k) h *= hp[(size_t)k * (BN * HID) + gi];
        sm[b][ii] = -(h * gate(qz2[ii]));
    }
    __syncthreads();

    float acc0 = 1.0f, acc1 = 1.0f, acc2 = 1.0f, acc3 = 1.0f;
    const float* wp = W2 + j;
    const float* sp = sm[bb];
#pragma unroll 4
    for (int i = 0; i < HID; i += 4) {
        float4 a4 = *reinterpret_cast<const float4*>(sp + i);  // uniform ds_read_b128
        acc0 *= fmaf(a4.x, wp[(size_t)(i + 0) * OUT], 1.0f);
        acc1 *= fmaf(a4.y, wp[(size_t)(i + 1) * OUT], 1.0f);
        acc2 *= fmaf(a4.z, wp[(size_t)(i + 2) * OUT], 1.0f);
        acc3 *= fmaf(a4.w, wp[(size_t)(i + 3) * OUT], 1.0f);
    }
    out[(size_t)(b0 + bb) * OUT + j] = 1.0f - ((acc0 * acc1) * (acc2 * acc3));
}

extern "C" void kernel_launch(void* const* d_in, const int* in_sizes, int n_in,
                              void* d_out, int out_size, void* d_ws, size_t ws_size,
                              hipStream_t stream) {
    const float* x   = (const float*)d_in[0];
    const float* W1  = (const float*)d_in[1];
    const float* qz1 = (const float*)d_in[2];
    const float* W2  = (const float*)d_in[3];
    const float* qz2 = (const float*)d_in[4];
    float* out = (float*)d_out;
    float* ws  = (float*)d_ws;

    // ws layout (floats): hp = KS1*BN*HID = 4M floats (16 MB)
    float* hp = ws;

    k_layer1 <<<dim3(BN / G, KS1), 256, 0, stream>>>(x, qz1, W1, hp);
    k_layer2f<<<256, 512, 0, stream>>>(hp, qz2, W2, out);
}

// Round 5
// 137.773 us; speedup vs baseline: 1.1833x; 1.1833x over previous
//
#include <hip/hip_runtime.h>
#include <math.h>

// Problem dims (fixed by reference)
#define BN  256
#define IN  512
#define HID 1024
#define OUT 512

typedef float f32x2 __attribute__((ext_vector_type(2)));

// hard-concrete deterministic gate: clip(sigmoid(q)*1.2 - 0.1, 0, 1)
__device__ __forceinline__ float gate(float q) {
    float s = 1.0f / (1.0f + expf(-q));
    return fminf(fmaxf(fmaf(s, 1.2f, -0.1f), 0.0f), 1.0f);
}

// K1 (fuzzy AND, full-K, no partials): h[b][j] = prod_{i<512} (1 + m[b][i]*W1[i][j])
// with m = x*z1 - 1. grid 256 = 16 bt x 16 jt; block 512 = 64 j x 8 waves,
// each wave owns 2 consecutive b-rows (packed f32x2), so W1 row reads are
// 256B coalesced and shared by all 8 waves (L1 hits), m reads are LDS broadcast.
__global__ __launch_bounds__(512) void k_layer1(
        const float* __restrict__ x, const float* __restrict__ qz1,
        const float* __restrict__ W1, float* __restrict__ h) {
    __shared__ float z1g[IN];       // 2 KB
    __shared__ float m[16][IN];     // 32 KB
    const int tid = threadIdx.x;
    const int bt = blockIdx.x >> 4, jt = blockIdx.x & 15;
    const int b0 = bt * 16, j0 = jt * 64;

    z1g[tid] = gate(qz1[tid]);      // 512 threads == IN
    __syncthreads();
#pragma unroll
    for (int p = 0; p < 16; ++p)    // coalesced x rows
        m[p][tid] = fmaf(x[(size_t)(b0 + p) * IN + tid], z1g[tid], -1.0f);
    __syncthreads();

    const int j  = j0 + (tid & 63);
    const int wv = tid >> 6;        // 0..7
    const int r0 = wv * 2, r1 = r0 + 1;
    const f32x2 one2 = {1.0f, 1.0f};
    f32x2 acc0 = one2, acc1 = one2;

    const float* wp = W1 + j;
#pragma unroll 2
    for (int i = 0; i < IN; i += 4) {
        float w0 = wp[(size_t)(i + 0) * HID];
        float w1 = wp[(size_t)(i + 1) * HID];
        float w2 = wp[(size_t)(i + 2) * HID];
        float w3 = wp[(size_t)(i + 3) * HID];
        float4 a0 = *reinterpret_cast<const float4*>(&m[r0][i]);  // broadcast
        float4 a1 = *reinterpret_cast<const float4*>(&m[r1][i]);
        f32x2 p0 = {a0.x, a1.x}, p1 = {a0.y, a1.y};
        f32x2 p2 = {a0.z, a1.z}, p3 = {a0.w, a1.w};
        acc0 *= p0 * f32x2{w0, w0} + one2;
        acc1 *= p1 * f32x2{w1, w1} + one2;
        acc0 *= p2 * f32x2{w2, w2} + one2;
        acc1 *= p3 * f32x2{w3, w3} + one2;
    }
    f32x2 t = acc0 * acc1;
    h[(size_t)(b0 + r0) * HID + j] = t[0];
    h[(size_t)(b0 + r1) * HID + j] = t[1];
}

// K2 (fuzzy OR, full-K, fused final): out[b][j] = 1 - prod_{i<1024} (1 + n[b][i]*W2[i][j])
// with n = -(h*z2). grid 256 = 32 bt x 8 jt; block 256 = 64 j x 4 waves x 2 rows.
__global__ __launch_bounds__(256) void k_layer2(
        const float* __restrict__ h, const float* __restrict__ qz2,
        const float* __restrict__ W2, float* __restrict__ out) {
    __shared__ float z2g[HID];      // 4 KB
    __shared__ float n[8][HID];     // 32 KB
    const int tid = threadIdx.x;
    const int bt = blockIdx.x >> 3, jt = blockIdx.x & 7;
    const int b0 = bt * 8, j0 = jt * 64;

#pragma unroll
    for (int q = 0; q < 4; ++q) {
        int ii = q * 256 + tid;
        z2g[ii] = gate(qz2[ii]);
    }
    __syncthreads();
#pragma unroll
    for (int b = 0; b < 8; ++b)
#pragma unroll
        for (int q = 0; q < 4; ++q) {   // coalesced h rows
            int ii = q * 256 + tid;
            n[b][ii] = -h[(size_t)(b0 + b) * HID + ii] * z2g[ii];
        }
    __syncthreads();

    const int j  = j0 + (tid & 63);
    const int wv = tid >> 6;        // 0..3
    const int r0 = wv * 2, r1 = r0 + 1;
    const f32x2 one2 = {1.0f, 1.0f};
    f32x2 acc0 = one2, acc1 = one2;

    const float* wp = W2 + j;
#pragma unroll 2
    for (int i = 0; i < HID; i += 4) {
        float w0 = wp[(size_t)(i + 0) * OUT];
        float w1 = wp[(size_t)(i + 1) * OUT];
        float w2 = wp[(size_t)(i + 2) * OUT];
        float w3 = wp[(size_t)(i + 3) * OUT];
        float4 a0 = *reinterpret_cast<const float4*>(&n[r0][i]);
        float4 a1 = *reinterpret_cast<const float4*>(&n[r1][i]);
        f32x2 p0 = {a0.x, a1.x}, p1 = {a0.y, a1.y};
        f32x2 p2 = {a0.z, a1.z}, p3 = {a0.w, a1.w};
        acc0 *= p0 * f32x2{w0, w0} + one2;
        acc1 *= p1 * f32x2{w1, w1} + one2;
        acc0 *= p2 * f32x2{w2, w2} + one2;
        acc1 *= p3 * f32x2{w3, w3} + one2;
    }
    f32x2 t = acc0 * acc1;
    out[(size_t)(b0 + r0) * OUT + j] = 1.0f - t[0];
    out[(size_t)(b0 + r1) * OUT + j] = 1.0f - t[1];
}

extern "C" void kernel_launch(void* const* d_in, const int* in_sizes, int n_in,
                              void* d_out, int out_size, void* d_ws, size_t ws_size,
                              hipStream_t stream) {
    const float* x   = (const float*)d_in[0];
    const float* W1  = (const float*)d_in[1];
    const float* qz1 = (const float*)d_in[2];
    const float* W2  = (const float*)d_in[3];
    const float* qz2 = (const float*)d_in[4];
    float* out = (float*)d_out;
    float* hbuf = (float*)d_ws;     // h: BN*HID floats = 1 MB

    k_layer1<<<256, 512, 0, stream>>>(x, qz1, W1, hbuf);
    k_layer2<<<256, 256, 0, stream>>>(hbuf, qz2, W2, out);
}

// Round 7
// 105.244 us; speedup vs baseline: 1.5490x; 1.3091x over previous
//
#include <hip/hip_runtime.h>
#include <math.h>

// Problem dims (fixed by reference)
#define BN  256
#define IN  512
#define HID 1024
#define OUT 512

#define KS1 8             // layer-1 K-split: 512 -> 8 chunks of 64
#define C1  (IN / KS1)    // 64
#define KS2 16            // layer-2 K-split: 1024 -> 16 chunks of 64
#define C2  (HID / KS2)   // 64

typedef float f32x2 __attribute__((ext_vector_type(2)));

// hard-concrete deterministic gate: clip(sigmoid(q)*1.2 - 0.1, 0, 1)
__device__ __forceinline__ float gate(float q) {
    float s = 1.0f / (1.0f + expf(-q));
    return fminf(fmaxf(fmaf(s, 1.2f, -0.1f), 0.0f), 1.0f);
}

// ---------------------------------------------------------------------------
// K1: layer-1 partials. hp[ks][b][j] = prod_{i in chunk ks} (1 + m[b][i]*W1[i][j])
// with m = x*z1 - 1  (so the fuzzy-AND term 1-(1-x*z1)*W = 1 + m*W).
// grid (jt=8, bt=32, ks=8) = 2048 blocks; block 256 = 8 b-groups x 32 lanes.
// thread: 4 consecutive j (float4 W loads), 1 b row; 8 waves/SIMD.
// ---------------------------------------------------------------------------
__global__ __launch_bounds__(256, 8) void k_layer1(
        const float* __restrict__ x, const float* __restrict__ qz1,
        const float* __restrict__ W1, float* __restrict__ hp) {
    __shared__ float m[8][C1];     // 2 KB
    const int tid = threadIdx.x;
    const int jt = blockIdx.x, bt = blockIdx.y, ks = blockIdx.z;
    const int b0 = bt * 8, j0 = jt * 128, i0 = ks * C1;

    // stage m: 512 elems, 2 per thread, coalesced over i
#pragma unroll
    for (int p = 0; p < 2; ++p) {
        int t = p * 256 + tid;
        int ii = t & 63, b = t >> 6;
        m[b][ii] = fmaf(x[(size_t)(b0 + b) * IN + i0 + ii],
                        gate(qz1[i0 + ii]), -1.0f);
    }
    __syncthreads();

    const int lane = tid & 31, grp = tid >> 5;
    const int j = j0 + lane * 4;
    const f32x2 one2 = {1.0f, 1.0f};
    f32x2 acc[2][2];               // [j-pair][parity]
#pragma unroll
    for (int a = 0; a < 2; ++a)
#pragma unroll
        for (int p = 0; p < 2; ++p) acc[a][p] = one2;

    const float* wp = W1 + (size_t)i0 * HID + j;
    const float* nrow = m[grp];
#pragma unroll 2
    for (int ii = 0; ii < C1; ii += 4) {
        float4 w0 = *reinterpret_cast<const float4*>(wp + (size_t)(ii + 0) * HID);
        float4 w1 = *reinterpret_cast<const float4*>(wp + (size_t)(ii + 1) * HID);
        float4 w2 = *reinterpret_cast<const float4*>(wp + (size_t)(ii + 2) * HID);
        float4 w3 = *reinterpret_cast<const float4*>(wp + (size_t)(ii + 3) * HID);
        float4 nn = *reinterpret_cast<const float4*>(nrow + ii);   // broadcast
        f32x2 n0 = {nn.x, nn.x}, n1 = {nn.y, nn.y};
        f32x2 n2 = {nn.z, nn.z}, n3 = {nn.w, nn.w};
        acc[0][0] *= f32x2{w0.x, w0.y} * n0 + one2;
        acc[1][0] *= f32x2{w0.z, w0.w} * n0 + one2;
        acc[0][1] *= f32x2{w1.x, w1.y} * n1 + one2;
        acc[1][1] *= f32x2{w1.z, w1.w} * n1 + one2;
        acc[0][0] *= f32x2{w2.x, w2.y} * n2 + one2;
        acc[1][0] *= f32x2{w2.z, w2.w} * n2 + one2;
        acc[0][1] *= f32x2{w3.x, w3.y} * n3 + one2;
        acc[1][1] *= f32x2{w3.z, w3.w} * n3 + one2;
    }
    f32x2 tA = acc[0][0] * acc[0][1];
    f32x2 tB = acc[1][0] * acc[1][1];
    float4 v = {tA[0], tA[1], tB[0], tB[1]};
    *reinterpret_cast<float4*>(
        hp + ((size_t)ks * BN + b0 + grp) * HID + j) = v;
}

// ---------------------------------------------------------------------------
// K2: layer-2 partials; staging fuses the KS1-way hp combine and z2 gate.
// pp[ks][b][j] = prod_{i in chunk ks} (1 - h[b][i]*z2[i]*W2[i][j])
// grid (jt=4, bt=32, ks=16) = 2048 blocks; same thread shape as K1.
// ---------------------------------------------------------------------------
__global__ __launch_bounds__(256, 8) void k_layer2(
        const float* __restrict__ hp, const float* __restrict__ qz2,
        const float* __restrict__ W2, float* __restrict__ pp) {
    __shared__ float n[8][C2];     // 2 KB: n = -(h*z2)
    const int tid = threadIdx.x;
    const int jt = blockIdx.x, bt = blockIdx.y, ks = blockIdx.z;
    const int b0 = bt * 8, j0 = jt * 128, i0 = ks * C2;

#pragma unroll
    for (int p = 0; p < 2; ++p) {
        int t = p * 256 + tid;
        int ii = t & 63, b = t >> 6;
        size_t gi = (size_t)(b0 + b) * HID + i0 + ii;
        float h = hp[gi];
#pragma unroll
        for (int k = 1; k < KS1; ++k) h *= hp[(size_t)k * (BN * HID) + gi];
        n[b][ii] = -(h * gate(qz2[i0 + ii]));
    }
    __syncthreads();

    const int lane = tid & 31, grp = tid >> 5;
    const int j = j0 + lane * 4;
    const f32x2 one2 = {1.0f, 1.0f};
    f32x2 acc[2][2];
#pragma unroll
    for (int a = 0; a < 2; ++a)
#pragma unroll
        for (int p = 0; p < 2; ++p) acc[a][p] = one2;

    const float* wp = W2 + (size_t)i0 * OUT + j;
    const float* nrow = n[grp];
#pragma unroll 2
    for (int ii = 0; ii < C2; ii += 4) {
        float4 w0 = *reinterpret_cast<const float4*>(wp + (size_t)(ii + 0) * OUT);
        float4 w1 = *reinterpret_cast<const float4*>(wp + (size_t)(ii + 1) * OUT);
        float4 w2 = *reinterpret_cast<const float4*>(wp + (size_t)(ii + 2) * OUT);
        float4 w3 = *reinterpret_cast<const float4*>(wp + (size_t)(ii + 3) * OUT);
        float4 nn = *reinterpret_cast<const float4*>(nrow + ii);
        f32x2 n0 = {nn.x, nn.x}, n1 = {nn.y, nn.y};
        f32x2 n2 = {nn.z, nn.z}, n3 = {nn.w, nn.w};
        acc[0][0] *= f32x2{w0.x, w0.y} * n0 + one2;
        acc[1][0] *= f32x2{w0.z, w0.w} * n0 + one2;
        acc[0][1] *= f32x2{w1.x, w1.y} * n1 + one2;
        acc[1][1] *= f32x2{w1.z, w1.w} * n1 + one2;
        acc[0][0] *= f32x2{w2.x, w2.y} * n2 + one2;
        acc[1][0] *= f32x2{w2.z, w2.w} * n2 + one2;
        acc[0][1] *= f32x2{w3.x, w3.y} * n3 + one2;
        acc[1][1] *= f32x2{w3.z, w3.w} * n3 + one2;
    }
    f32x2 tA = acc[0][0] * acc[0][1];
    f32x2 tB = acc[1][0] * acc[1][1];
    float4 v = {tA[0], tA[1], tB[0], tB[1]};
    *reinterpret_cast<float4*>(
        pp + ((size_t)ks * BN + b0 + grp) * OUT + j) = v;
}

// ---------------------------------------------------------------------------
// K3: final combine. out[b][j] = 1 - prod_{ks<16} pp[ks][b][j]
// 16 independent strided loads per thread, multiply tree.
// ---------------------------------------------------------------------------
__global__ __launch_bounds__(256) void k_final(
        const float* __restrict__ pp, float* __restrict__ out) {
    int idx = blockIdx.x * 256 + threadIdx.x;
    float v[KS2];
#pragma unroll
    for (int k = 0; k < KS2; ++k) v[k] = pp[(size_t)k * (BN * OUT) + idx];
#pragma unroll
    for (int s = KS2 / 2; s > 0; s >>= 1)
#pragma unroll
        for (int k = 0; k < s; ++k) v[k] *= v[k + s];
    out[idx] = 1.0f - v[0];
}

extern "C" void kernel_launch(void* const* d_in, const int* in_sizes, int n_in,
                              void* d_out, int out_size, void* d_ws, size_t ws_size,
                              hipStream_t stream) {
    const float* x   = (const float*)d_in[0];
    const float* W1  = (const float*)d_in[1];
    const float* qz1 = (const float*)d_in[2];
    const float* W2  = (const float*)d_in[3];
    const float* qz2 = (const float*)d_in[4];
    float* out = (float*)d_out;
    float* ws  = (float*)d_ws;

    // ws (floats): hp = KS1*BN*HID = 2M (8 MB); pp = KS2*BN*OUT = 2M (8 MB)
    float* hp = ws;
    float* pp = ws + (size_t)KS1 * BN * HID;

    k_layer1<<<dim3(8, 32, KS1), 256, 0, stream>>>(x, qz1, W1, hp);
    k_layer2<<<dim3(4, 32, KS2), 256, 0, stream>>>(hp, qz2, W2, pp);
    k_final <<<(BN * OUT) / 256, 256, 0, stream>>>(pp, out);
}

// Round 8
// 101.139 us; speedup vs baseline: 1.6119x; 1.0406x over previous
//
#include <hip/hip_runtime.h>
#include <math.h>

// Problem dims (fixed by reference)
#define BN  256
#define IN  512
#define HID 1024
#define OUT 512

#define KS1 8             // layer-1 K-split: 512 -> 8 chunks of 64
#define C1  (IN / KS1)    // 64

typedef float f32x2 __attribute__((ext_vector_type(2)));

// hard-concrete deterministic gate: clip(sigmoid(q)*1.2 - 0.1, 0, 1)
__device__ __forceinline__ float gate(float q) {
    float s = 1.0f / (1.0f + expf(-q));
    return fminf(fmaxf(fmaf(s, 1.2f, -0.1f), 0.0f), 1.0f);
}

// ---------------------------------------------------------------------------
// K1 (verbatim from R7, proven): layer-1 partials.
// hp[ks][b][j] = prod_{i in chunk ks} (1 + m[b][i]*W1[i][j]), m = x*z1 - 1.
// grid (jt=8, bt=32, ks=8) = 2048 blocks; 8 waves/SIMD.
// ---------------------------------------------------------------------------
__global__ __launch_bounds__(256, 8) void k_layer1(
        const float* __restrict__ x, const float* __restrict__ qz1,
        const float* __restrict__ W1, float* __restrict__ hp) {
    __shared__ float m[8][C1];     // 2 KB
    const int tid = threadIdx.x;
    const int jt = blockIdx.x, bt = blockIdx.y, ks = blockIdx.z;
    const int b0 = bt * 8, j0 = jt * 128, i0 = ks * C1;

#pragma unroll
    for (int p = 0; p < 2; ++p) {
        int t = p * 256 + tid;
        int ii = t & 63, b = t >> 6;
        m[b][ii] = fmaf(x[(size_t)(b0 + b) * IN + i0 + ii],
                        gate(qz1[i0 + ii]), -1.0f);
    }
    __syncthreads();

    const int lane = tid & 31, grp = tid >> 5;
    const int j = j0 + lane * 4;
    const f32x2 one2 = {1.0f, 1.0f};
    f32x2 acc[2][2];
#pragma unroll
    for (int a = 0; a < 2; ++a)
#pragma unroll
        for (int p = 0; p < 2; ++p) acc[a][p] = one2;

    const float* wp = W1 + (size_t)i0 * HID + j;
    const float* nrow = m[grp];
#pragma unroll 2
    for (int ii = 0; ii < C1; ii += 4) {
        float4 w0 = *reinterpret_cast<const float4*>(wp + (size_t)(ii + 0) * HID);
        float4 w1 = *reinterpret_cast<const float4*>(wp + (size_t)(ii + 1) * HID);
        float4 w2 = *reinterpret_cast<const float4*>(wp + (size_t)(ii + 2) * HID);
        float4 w3 = *reinterpret_cast<const float4*>(wp + (size_t)(ii + 3) * HID);
        float4 nn = *reinterpret_cast<const float4*>(nrow + ii);   // broadcast
        f32x2 n0 = {nn.x, nn.x}, n1 = {nn.y, nn.y};
        f32x2 n2 = {nn.z, nn.z}, n3 = {nn.w, nn.w};
        acc[0][0] *= f32x2{w0.x, w0.y} * n0 + one2;
        acc[1][0] *= f32x2{w0.z, w0.w} * n0 + one2;
        acc[0][1] *= f32x2{w1.x, w1.y} * n1 + one2;
        acc[1][1] *= f32x2{w1.z, w1.w} * n1 + one2;
        acc[0][0] *= f32x2{w2.x, w2.y} * n2 + one2;
        acc[1][0] *= f32x2{w2.z, w2.w} * n2 + one2;
        acc[0][1] *= f32x2{w3.x, w3.y} * n3 + one2;
        acc[1][1] *= f32x2{w3.z, w3.w} * n3 + one2;
    }
    f32x2 tA = acc[0][0] * acc[0][1];
    f32x2 tB = acc[1][0] * acc[1][1];
    float4 v = {tA[0], tA[1], tB[0], tB[1]};
    *reinterpret_cast<float4*>(
        hp + ((size_t)ks * BN + b0 + grp) * HID + j) = v;
}

// ---------------------------------------------------------------------------
// K2: fused layer-2 + final combine (k_final node eliminated).
// out[b][j] = 1 - prod_{i<1024} (1 - h[b][i]*z2[i]*W2[i][j]); h = prod_k hp[k].
// grid (jt=8, bt=32) = 256 blocks; block 1024 thr = 4 kc x 4 bp x 64 lanes
// (16 waves/CU = 4/SIMD). Intra-block K-split; partials combined in LDS.
// ---------------------------------------------------------------------------
__global__ __launch_bounds__(1024, 4) void k_layer2f(
        const float* __restrict__ hp, const float* __restrict__ qz2,
        const float* __restrict__ W2, float* __restrict__ out) {
    __shared__ f32x2 n2[4][HID];     // [bp][i] = {-h*z2 for b=2bp, 2bp+1}  32 KB
    __shared__ f32x2 sm2[4][4][64];  // [kc][bp][lane] partial products      8 KB
    const int tid = threadIdx.x;
    const int jt = blockIdx.x, bt = blockIdx.y;
    const int b0 = bt * 8, j0 = jt * 64;

    // stage n = -(h*z2): 1024 threads == HID columns; 8 batch rows.
    const float z2v = gate(qz2[tid]);          // one expf per thread
#pragma unroll
    for (int p = 0; p < 8; ++p) {
        size_t gi = (size_t)(b0 + p) * HID + tid;
        float h = hp[gi];
#pragma unroll
        for (int k = 1; k < KS1; ++k) h *= hp[(size_t)k * (BN * HID) + gi];
        n2[p >> 1][tid][p & 1] = -(h * z2v);   // stride-8B writes: conflict-free
    }
    __syncthreads();

    const int kc   = tid >> 8;        // 0..3  K-chunk of 256
    const int r    = tid & 255;
    const int bp   = r >> 6;          // 0..3  batch-row pair
    const int lane = r & 63;
    const int j    = j0 + lane;
    const int i0   = kc * 256;

    const f32x2 one2 = {1.0f, 1.0f};
    f32x2 accA = one2, accB = one2;
    const float* wp = W2 + (size_t)i0 * OUT + j;
    const f32x2* np = &n2[bp][i0];
#pragma unroll 8
    for (int i = 0; i < 256; i += 2) {
        float w0 = wp[(size_t)(i + 0) * OUT];   // lane-coalesced 256B rows
        float w1 = wp[(size_t)(i + 1) * OUT];
        f32x2 nv0 = np[i + 0];                  // 8B broadcast reads
        f32x2 nv1 = np[i + 1];
        accA *= nv0 * f32x2{w0, w0} + one2;
        accB *= nv1 * f32x2{w1, w1} + one2;
    }
    sm2[kc][bp][lane] = accA * accB;
    __syncthreads();

    if (tid < 512) {                  // 8 b x 64 j outputs
        int jj = tid & 63, b = tid >> 6;
        int bq = b >> 1, hh = b & 1;
        float p0 = sm2[0][bq][jj][hh] * sm2[1][bq][jj][hh];
        float p1 = sm2[2][bq][jj][hh] * sm2[3][bq][jj][hh];
        out[(size_t)(b0 + b) * OUT + j0 + jj] = 1.0f - p0 * p1;
    }
}

extern "C" void kernel_launch(void* const* d_in, const int* in_sizes, int n_in,
                              void* d_out, int out_size, void* d_ws, size_t ws_size,
                              hipStream_t stream) {
    const float* x   = (const float*)d_in[0];
    const float* W1  = (const float*)d_in[1];
    const float* qz1 = (const float*)d_in[2];
    const float* W2  = (const float*)d_in[3];
    const float* qz2 = (const float*)d_in[4];
    float* out = (float*)d_out;
    float* ws  = (float*)d_ws;

    // ws (floats): hp = KS1*BN*HID = 2M (8 MB)
    float* hp = ws;

    k_layer1 <<<dim3(8, 32, KS1), 256, 0, stream>>>(x, qz1, W1, hp);
    k_layer2f<<<dim3(8, 32),     1024, 0, stream>>>(hp, qz2, W2, out);
}